// Round 16
// baseline (101.164 us; speedup 1.0000x reference)
//
#include <hip/hip_runtime.h>
#include <hip/hip_bf16.h>

typedef float f32x4 __attribute__((ext_vector_type(4)));
typedef _Float16 half8 __attribute__((ext_vector_type(8)));
typedef _Float16 half4 __attribute__((ext_vector_type(4)));
typedef __fp16 cvt2_t __attribute__((ext_vector_type(2)));

#define N_NODES 1024
#define FDIM 64
#define NG 32   // B * Tp = 2 * 16
#define LOG2E 1.44269504088896f

// ---------------- K0: fused prep — 0x00/0xFF byte mask + weight transpose ----------------
__global__ __launch_bounds__(256) void k_prep(const int* __restrict__ adj,
                                              const float* __restrict__ Wh,
                                              const float* __restrict__ Wo,
                                              unsigned char* __restrict__ Mbyte,
                                              _Float16* __restrict__ wt1,
                                              _Float16* __restrict__ wt2) {
    const int bb = blockIdx.x, t = threadIdx.x;
    if (bb < 128) {
        int w = bb * 256 + t;                  // 32768 threads x 32 elements
        const int* p = adj + (size_t)w * 32;
        unsigned r[8];
#pragma unroll
        for (int q = 0; q < 8; q++) {
            int4 a = ((const int4*)p)[q];
            r[q] = (a.x > 0 ? 0xFFu : 0u) | (a.y > 0 ? 0xFFu << 8 : 0u) |
                   (a.z > 0 ? 0xFFu << 16 : 0u) | (a.w > 0 ? 0xFFu << 24 : 0u);
        }
        uint4* dst = (uint4*)(Mbyte + (size_t)w * 32);
        dst[0] = (uint4){r[0], r[1], r[2], r[3]};
        dst[1] = (uint4){r[4], r[5], r[6], r[7]};
    } else if (bb < 132) {
        const int row = (bb - 128) * 64 + (t >> 2);   // 0..255 = h*64+o
        const int kq = t & 3;
        const float* src = Wh + (size_t)(row >> 6) * 4096 + (row & 63);
#pragma unroll
        for (int kk = 0; kk < 16; kk += 8) {
            const int k0 = kq * 16 + kk;
            union { half8 v; cvt2_t c[4]; } pk_;
#pragma unroll
            for (int j = 0; j < 8; j += 2)
                pk_.c[j >> 1] = __builtin_amdgcn_cvt_pkrtz(src[(k0 + j) * 64],
                                                           src[(k0 + j + 1) * 64]);
            *(half8*)(wt1 + (size_t)row * 64 + k0) = pk_.v;
        }
    } else {
        const int o = (bb - 132) * 16 + (t >> 4);     // 0..63
        const int k0 = (t & 15) * 16;
        const float* src = Wo + o;
#pragma unroll
        for (int kk = 0; kk < 16; kk += 8) {
            union { half8 v; cvt2_t c[4]; } pk_;
#pragma unroll
            for (int j = 0; j < 8; j += 2)
                pk_.c[j >> 1] = __builtin_amdgcn_cvt_pkrtz(src[(k0 + kk + j) * 64],
                                                           src[(k0 + kk + j + 1) * 64]);
            *(half8*)(wt2 + (size_t)o * 256 + k0 + kk) = pk_.v;
        }
    }
}

// ---------------- K1: layer-1 projection via fp16 MFMA (4 heads fused) ----------------
// epilogue stores: K=2^(-0.8*phi1), EB=2^phi2, ED=2^(0.2*phi2)  (all f32)
__global__ __launch_bounds__(512, 2) void k_proj1(const float* __restrict__ x,
                                                  const _Float16* __restrict__ wt1,
                                                  const float* __restrict__ ah,
                                                  _Float16* __restrict__ H1T,
                                                  float* __restrict__ Kv,
                                                  float* __restrict__ EB,
                                                  float* __restrict__ ED) {
    __shared__ _Float16 xs[128][64];   // XOR-swizzled 16B units
    const int t = threadIdx.x;
    const int nb = blockIdx.x, g = blockIdx.y;
    const int n0 = nb * 128;
    const int b = g >> 4, tstep = g & 15;

    {   // stage x tile
        const int r = t >> 2, cq = t & 3;
        const float* xr = x + (((size_t)(b * 17 + tstep) * N_NODES + n0 + r) * FDIM) + cq * 16;
        float4 v0 = *(const float4*)(xr);
        float4 v1 = *(const float4*)(xr + 4);
        float4 v2 = *(const float4*)(xr + 8);
        float4 v3 = *(const float4*)(xr + 12);
        union { half8 v; cvt2_t c[4]; } u0, u1;
        u0.c[0] = __builtin_amdgcn_cvt_pkrtz(v0.x, v0.y);
        u0.c[1] = __builtin_amdgcn_cvt_pkrtz(v0.z, v0.w);
        u0.c[2] = __builtin_amdgcn_cvt_pkrtz(v1.x, v1.y);
        u0.c[3] = __builtin_amdgcn_cvt_pkrtz(v1.z, v1.w);
        u1.c[0] = __builtin_amdgcn_cvt_pkrtz(v2.x, v2.y);
        u1.c[1] = __builtin_amdgcn_cvt_pkrtz(v2.z, v2.w);
        u1.c[2] = __builtin_amdgcn_cvt_pkrtz(v3.x, v3.y);
        u1.c[3] = __builtin_amdgcn_cvt_pkrtz(v3.z, v3.w);
        *(half8*)&xs[r][((2 * cq) ^ (r & 7)) * 8] = u0.v;
        *(half8*)&xs[r][((2 * cq + 1) ^ (r & 7)) * 8] = u1.v;
    }
    __syncthreads();

    const int wv = t >> 6, ln = t & 63, li = ln & 15, grp = ln >> 4;
    const int arow = wv * 16 + li;

    f32x4 acc[16];
#pragma unroll
    for (int q = 0; q < 16; q++) acc[q] = (f32x4){0.f, 0.f, 0.f, 0.f};

#pragma unroll
    for (int s = 0; s < 2; s++) {
        half8 af = *(const half8*)&xs[arow][((s * 4 + grp) ^ (arow & 7)) * 8];
#pragma unroll
        for (int tile = 0; tile < 16; tile++) {
            half8 bf = *(const half8*)(wt1 + (size_t)(tile * 16 + li) * 64 + s * 32 + grp * 8);
            acc[tile] = __builtin_amdgcn_mfma_f32_16x16x32_f16(af, bf, acc[tile], 0, 0, 0);
        }
    }

    const int nbase = n0 + wv * 16 + grp * 4;
#pragma unroll
    for (int h = 0; h < 4; h++) {
        float p1[4] = {0.f, 0.f, 0.f, 0.f}, p2[4] = {0.f, 0.f, 0.f, 0.f};
#pragma unroll
        for (int ot = 0; ot < 4; ot++) {
            float a1v = ah[h * 128 + ot * 16 + li];
            float a2v = ah[h * 128 + 64 + ot * 16 + li];
            f32x4 A = acc[h * 4 + ot];
#pragma unroll
            for (int r = 0; r < 4; r++) {
                p1[r] = fmaf(A[r], a1v, p1[r]);
                p2[r] = fmaf(A[r], a2v, p2[r]);
            }
        }
#pragma unroll
        for (int m = 1; m < 16; m <<= 1)
#pragma unroll
            for (int r = 0; r < 4; r++) {
                p1[r] += __shfl_xor(p1[r], m);
                p2[r] += __shfl_xor(p2[r], m);
            }
        if (li == 0) {
            const size_t gh = (size_t)h * NG + g;
#pragma unroll
            for (int r = 0; r < 4; r++) {
                float phi1 = p1[r] * LOG2E, phi2 = p2[r] * LOG2E;
                Kv[gh * N_NODES + nbase + r] = __builtin_amdgcn_exp2f(-0.8f * phi1);
                EB[gh * N_NODES + nbase + r] = __builtin_amdgcn_exp2f(phi2);
                ED[gh * N_NODES + nbase + r] = __builtin_amdgcn_exp2f(0.2f * phi2);
            }
        }
    }
#pragma unroll
    for (int tile = 0; tile < 16; tile++) {
        const int h = tile >> 2, ot = tile & 3;
        union { half4 v; cvt2_t c[2]; } st;
        st.c[0] = __builtin_amdgcn_cvt_pkrtz(acc[tile][0], acc[tile][1]);
        st.c[1] = __builtin_amdgcn_cvt_pkrtz(acc[tile][2], acc[tile][3]);
        _Float16* dst = H1T + (((size_t)h * NG + g) * FDIM + ot * 16 + li) * N_NODES + nbase;
        *(half4*)dst = st.v;
    }
}

// q-pair: fp32 max(EB, K*ED) -> packed fp16 -> AND with perm-expanded byte mask
#define QPAIR(dst, kv, eax, eay, ecx, ecy, wsrc, sel)                          \
    { union { cvt2_t c; unsigned u; } _t;                                      \
      _t.c = __builtin_amdgcn_cvt_pkrtz(fmaxf(eax, (kv) * (ecx)),              \
                                        fmaxf(eay, (kv) * (ecy)));             \
      dst = _t.u & __builtin_amdgcn_perm(wsrc, wsrc, sel); }

// ---------------- fused masked attention (NW waves, NT row-tiles/wave) ----------------
// Double-buffered vt (round-8-verified 1-barrier-per-jt pipeline); fp32 scores;
// perm-AND byte mask; ones-MFMA row-sums; B-frag shared across NT row-tiles.
template<int CONCAT, int NT, int NW>
__global__ __launch_bounds__(NW * 64, 2) void k_attn(
    const _Float16* __restrict__ HT,         // [G][64 f][1024 n] f16
    const float* __restrict__ Kv,            // [G][1024] 2^(-0.8 phi1)
    const float* __restrict__ EBg,           // [G][1024] 2^(phi2)
    const float* __restrict__ EDg,           // [G][1024] 2^(0.2 phi2)
    const unsigned char* __restrict__ Mb,    // [1024][1024] byte mask {0,0xFF}
    _Float16* __restrict__ HC,               // concat out (CONCAT=1)
    float* __restrict__ out)                 // final out (CONCAT=0)
{
    __shared__ _Float16 vt[2][64][256];      // 64KB double buffer; unit-XOR swizzle
    __shared__ float ebs[N_NODES];           // 4KB
    __shared__ float eds[N_NODES];           // 4KB
    const int t = threadIdx.x;
    const int g = blockIdx.x, h = blockIdx.y, nb = blockIdx.z;
    const int i0 = nb * (NW * NT * 16);
    const size_t gidx = CONCAT ? ((size_t)h * NG + g) : (size_t)g;

    {   // stage fp32 score vectors
        const float* ebsrc = EBg + gidx * N_NODES;
        const float* edsrc = EDg + gidx * N_NODES;
        if (NW == 8) {
            ((float2*)ebs)[t] = ((const float2*)ebsrc)[t];
            ((float2*)eds)[t] = ((const float2*)edsrc)[t];
        } else {
            ((float4*)ebs)[t] = ((const float4*)ebsrc)[t];
            ((float4*)eds)[t] = ((const float4*)edsrc)[t];
        }
    }

    const int wv = t >> 6, ln = t & 63;
    const int li = ln & 15, grp = ln >> 4, jb = grp * 8;
    const int lx = li & 7;
    const int row0 = i0 + wv * (NT * 16) + li;

    float kv[NT];
    const unsigned char* Mr[NT];
    uint2 m0[NT], m1[NT];
#pragma unroll
    for (int ti = 0; ti < NT; ti++) {
        kv[ti] = Kv[gidx * N_NODES + row0 + ti * 16];
        Mr[ti] = Mb + (size_t)(row0 + ti * 16) * N_NODES + jb;
    }

    const _Float16* Hg = HT + gidx * (size_t)(FDIM * N_NODES);
    const int srow0 = t >> 3;                     // NW=8: 0..63 ; NW=4: 0..31 (+32)
    const int sxu = t & 7;                        // 8 lanes/row -> 128B contiguous
    const _Float16* srcA = Hg + (size_t)srow0 * N_NODES + sxu * 8;
    const int swA = sxu ^ (srow0 & 7);            // (srow0+32)&7 == srow0&7

    f32x4 acc[NT][4], acc5[NT];
#pragma unroll
    for (int ti = 0; ti < NT; ti++) {
#pragma unroll
        for (int q = 0; q < 4; q++) acc[ti][q] = (f32x4){0.f, 0.f, 0.f, 0.f};
        acc5[ti] = (f32x4){0.f, 0.f, 0.f, 0.f};
    }

    union { half8 v; unsigned short s[8]; } onesu;
#pragma unroll
    for (int q = 0; q < 8; q++) onesu.s[q] = 0x3C00;   // fp16 1.0
    const half8 ones = onesu.v;

    half8 stg[NW == 4 ? 8 : 4];
    // prologue: vt[0] <- jt0 ; stg <- jt1
#pragma unroll
    for (int k2 = 0; k2 < 4; k2++) stg[k2] = *(const half8*)(srcA + k2 * 64);
    if (NW == 4) {
#pragma unroll
        for (int k2 = 0; k2 < 4; k2++)
            stg[4 + k2] = *(const half8*)(srcA + 32 * N_NODES + k2 * 64);
    }
#pragma unroll
    for (int k2 = 0; k2 < 4; k2++)
        *(half8*)&vt[0][srow0][(k2 * 8 + swA) * 8] = stg[k2];
    if (NW == 4) {
#pragma unroll
        for (int k2 = 0; k2 < 4; k2++)
            *(half8*)&vt[0][srow0 + 32][(k2 * 8 + swA) * 8] = stg[4 + k2];
    }
#pragma unroll
    for (int k2 = 0; k2 < 4; k2++) stg[k2] = *(const half8*)(srcA + 256 + k2 * 64);
    if (NW == 4) {
#pragma unroll
        for (int k2 = 0; k2 < 4; k2++)
            stg[4 + k2] = *(const half8*)(srcA + 32 * N_NODES + 256 + k2 * 64);
    }
#pragma unroll
    for (int ti = 0; ti < NT; ti++) {
        m0[ti] = *(const uint2*)Mr[ti];
        m1[ti] = *(const uint2*)(Mr[ti] + 32);
    }
    __syncthreads();                               // vt[0] + score LDS ready

#pragma unroll
    for (int jt = 0; jt < 4; jt++) {
        if (jt < 3) {                              // write next buf (overlaps compute)
#pragma unroll
            for (int k2 = 0; k2 < 4; k2++)
                *(half8*)&vt[(jt + 1) & 1][srow0][(k2 * 8 + swA) * 8] = stg[k2];
            if (NW == 4) {
#pragma unroll
                for (int k2 = 0; k2 < 4; k2++)
                    *(half8*)&vt[(jt + 1) & 1][srow0 + 32][(k2 * 8 + swA) * 8] = stg[4 + k2];
            }
        }
        if (jt < 2) {                              // issue jt+2 global loads
#pragma unroll
            for (int k2 = 0; k2 < 4; k2++)
                stg[k2] = *(const half8*)(srcA + (jt + 2) * 256 + k2 * 64);
            if (NW == 4) {
#pragma unroll
                for (int k2 = 0; k2 < 4; k2++)
                    stg[4 + k2] = *(const half8*)(srcA + 32 * N_NODES + (jt + 2) * 256 + k2 * 64);
            }
        }

#pragma unroll
        for (int jc = 0; jc < 8; jc++) {
            uint2 w[NT];
#pragma unroll
            for (int ti = 0; ti < NT; ti++) {
                w[ti] = m0[ti];
                m0[ti] = m1[ti];
                if (!(jt == 3 && jc >= 6))
                    m1[ti] = *(const uint2*)(Mr[ti] + 64);
                Mr[ti] += 32;
            }

            const float* ebp = &ebs[jt * 256 + jc * 32 + jb];
            const float* edp = &eds[jt * 256 + jc * 32 + jb];
            float4 ea0 = *(const float4*)ebp;
            float4 ea1 = *(const float4*)(ebp + 4);
            float4 ec0 = *(const float4*)edp;
            float4 ec1 = *(const float4*)(edp + 4);

            union { half8 v; unsigned u[4]; } af[NT];
#pragma unroll
            for (int ti = 0; ti < NT; ti++) {
                QPAIR(af[ti].u[0], kv[ti], ea0.x, ea0.y, ec0.x, ec0.y, w[ti].x, 0x01010000u);
                QPAIR(af[ti].u[1], kv[ti], ea0.z, ea0.w, ec0.z, ec0.w, w[ti].x, 0x03030202u);
                QPAIR(af[ti].u[2], kv[ti], ea1.x, ea1.y, ec1.x, ec1.y, w[ti].y, 0x01010000u);
                QPAIR(af[ti].u[3], kv[ti], ea1.z, ea1.w, ec1.z, ec1.w, w[ti].y, 0x03030202u);
            }

            const int ub = (jc >> 1) * 8 + (((jc & 1) * 4 + grp) ^ lx);
#pragma unroll
            for (int q = 0; q < 4; q++) {     // B-frag shared by all row-tiles
                half8 bfr = *(const half8*)&vt[jt & 1][q * 16 + li][ub * 8];
#pragma unroll
                for (int ti = 0; ti < NT; ti++)
                    acc[ti][q] = __builtin_amdgcn_mfma_f32_16x16x32_f16(af[ti].v, bfr, acc[ti][q], 0, 0, 0);
            }
#pragma unroll
            for (int ti = 0; ti < NT; ti++)
                acc5[ti] = __builtin_amdgcn_mfma_f32_16x16x32_f16(af[ti].v, ones, acc5[ti], 0, 0, 0);
        }
        if (jt < 3) __syncthreads();               // single barrier per jt
    }

#pragma unroll
    for (int ti = 0; ti < NT; ti++) {
        float rin[4];
#pragma unroll
        for (int r2 = 0; r2 < 4; r2++) rin[r2] = 1.0f / acc5[ti][r2];
        if (CONCAT) {
            _Float16* HCg = HC + (size_t)g * N_NODES * 256 + h * 64;
#pragma unroll
            for (int q = 0; q < 4; q++)
#pragma unroll
                for (int r2 = 0; r2 < 4; r2++) {
                    int ir = i0 + wv * (NT * 16) + ti * 16 + grp * 4 + r2;
                    float v = acc[ti][q][r2] * rin[r2];
                    v = v > 0.f ? v : expm1f(v); // ELU
                    HCg[(size_t)ir * 256 + q * 16 + li] = (_Float16)v;
                }
        } else {
            float* og = out + (size_t)g * N_NODES * FDIM;
#pragma unroll
            for (int q = 0; q < 4; q++)
#pragma unroll
                for (int r2 = 0; r2 < 4; r2++) {
                    int ir = i0 + wv * (NT * 16) + ti * 16 + grp * 4 + r2;
                    float v = acc[ti][q][r2] * rin[r2];
                    og[(size_t)ir * FDIM + q * 16 + li] = v > 0.f ? v : 0.f;
                }
        }
    }
}

// ---------------- K3: layer-2 projection via fp16 MFMA ----------------
__global__ __launch_bounds__(512, 2) void k_proj2(const _Float16* __restrict__ HC,
                                                  const _Float16* __restrict__ wt2,
                                                  const float* __restrict__ ao,
                                                  _Float16* __restrict__ H2T,
                                                  float* __restrict__ Kv2,
                                                  float* __restrict__ EB2,
                                                  float* __restrict__ ED2) {
    __shared__ _Float16 xs[128][256];  // 64KB, XOR-swizzled within 8-unit groups
    const int t = threadIdx.x;
    const int nb = blockIdx.x, g = blockIdx.y;
    const int n0 = nb * 128;

    {   // stage HC tile
        const int r = t >> 2, cq = t & 3;
        const _Float16* src = HC + ((size_t)g * N_NODES + n0 + r) * 256 + cq * 64;
#pragma unroll
        for (int uu = 0; uu < 8; uu++) {
            int u = cq * 8 + uu;
            half8 v = *(const half8*)(src + uu * 8);
            int us = (u & 24) | ((u ^ r) & 7);
            *(half8*)&xs[r][us * 8] = v;
        }
    }
    __syncthreads();

    const int wv = t >> 6, ln = t & 63, li = ln & 15, grp = ln >> 4;
    const int arow = wv * 16 + li;

    f32x4 acc[4];
#pragma unroll
    for (int q = 0; q < 4; q++) acc[q] = (f32x4){0.f, 0.f, 0.f, 0.f};

#pragma unroll
    for (int s = 0; s < 8; s++) {
        int u = s * 4 + grp;
        int us = (u & 24) | ((u ^ arow) & 7);
        half8 af = *(const half8*)&xs[arow][us * 8];
#pragma unroll
        for (int tile = 0; tile < 4; tile++) {
            half8 bf = *(const half8*)(wt2 + (size_t)(tile * 16 + li) * 256 + s * 32 + grp * 8);
            acc[tile] = __builtin_amdgcn_mfma_f32_16x16x32_f16(af, bf, acc[tile], 0, 0, 0);
        }
    }

    const int nbase = n0 + wv * 16 + grp * 4;
    {
        float p1[4] = {0.f, 0.f, 0.f, 0.f}, p2[4] = {0.f, 0.f, 0.f, 0.f};
#pragma unroll
        for (int ot = 0; ot < 4; ot++) {
            float a1v = ao[ot * 16 + li];
            float a2v = ao[64 + ot * 16 + li];
            f32x4 A = acc[ot];
#pragma unroll
            for (int r = 0; r < 4; r++) {
                p1[r] = fmaf(A[r], a1v, p1[r]);
                p2[r] = fmaf(A[r], a2v, p2[r]);
            }
        }
#pragma unroll
        for (int m = 1; m < 16; m <<= 1)
#pragma unroll
            for (int r = 0; r < 4; r++) {
                p1[r] += __shfl_xor(p1[r], m);
                p2[r] += __shfl_xor(p2[r], m);
            }
        if (li == 0) {
#pragma unroll
            for (int r = 0; r < 4; r++) {
                float phi1 = p1[r] * LOG2E, phi2 = p2[r] * LOG2E;
                Kv2[(size_t)g * N_NODES + nbase + r] = __builtin_amdgcn_exp2f(-0.8f * phi1);
                EB2[(size_t)g * N_NODES + nbase + r] = __builtin_amdgcn_exp2f(phi2);
                ED2[(size_t)g * N_NODES + nbase + r] = __builtin_amdgcn_exp2f(0.2f * phi2);
            }
        }
    }
#pragma unroll
    for (int tile = 0; tile < 4; tile++) {
        union { half4 v; cvt2_t c[2]; } st;
        st.c[0] = __builtin_amdgcn_cvt_pkrtz(acc[tile][0], acc[tile][1]);
        st.c[1] = __builtin_amdgcn_cvt_pkrtz(acc[tile][2], acc[tile][3]);
        _Float16* dst = H2T + ((size_t)g * FDIM + tile * 16 + li) * N_NODES + nbase;
        *(half4*)dst = st.v;
    }
}

extern "C" void kernel_launch(void* const* d_in, const int* in_sizes, int n_in,
                              void* d_out, int out_size, void* d_ws, size_t ws_size,
                              hipStream_t stream) {
    const float* x  = (const float*)d_in[0];
    const int* adj  = (const int*)d_in[1];
    const float* Wh = (const float*)d_in[2];
    const float* ah = (const float*)d_in[3];
    const float* Wo = (const float*)d_in[4];
    const float* ao = (const float*)d_in[5];

    char* ws = (char*)d_ws;
    unsigned char* Mbyte = (unsigned char*)(ws);             // 1 MB
    _Float16* wt1 = (_Float16*)(ws + 1048576);               // 32 KB
    _Float16* wt2 = (_Float16*)(ws + 1081344);               // 32 KB
    float* Kv1 = (float*)(ws + 1114112);                     // 512 KB
    float* EB1 = (float*)(ws + 1638400);                     // 512 KB
    float* ED1 = (float*)(ws + 2162688);                     // 512 KB
    float* Kv2 = (float*)(ws + 2686976);                     // 128 KB
    float* EB2 = (float*)(ws + 2818048);                     // 128 KB
    float* ED2 = (float*)(ws + 2949120);                     // 128 KB
    _Float16* H1T = (_Float16*)(ws + 3080192);               // 16 MB
    _Float16* HC  = (_Float16*)(ws + 3080192 + 16777216);    // 16 MB
    _Float16* H2T = (_Float16*)(ws + 3080192 + 33554432);    //  4 MB
    float* out = (float*)d_out;

    k_prep       <<<dim3(136),       dim3(256), 0, stream>>>(adj, Wh, Wo, Mbyte, wt1, wt2);
    k_proj1      <<<dim3(8, 32),     dim3(512), 0, stream>>>(x, wt1, ah, H1T, Kv1, EB1, ED1);
    k_attn<1,4,8><<<dim3(32, 4, 2),  dim3(512), 0, stream>>>(H1T, Kv1, EB1, ED1, Mbyte, HC, nullptr);
    k_proj2      <<<dim3(8, 32),     dim3(512), 0, stream>>>(HC, wt2, ao, H2T, Kv2, EB2, ED2);
    k_attn<0,1,4><<<dim3(32, 1, 16), dim3(256), 0, stream>>>(H2T, Kv2, EB2, ED2, Mbyte, nullptr, out);
}

// Round 17
// 97.601 us; speedup vs baseline: 1.0365x; 1.0365x over previous
//
#include <hip/hip_runtime.h>
#include <hip/hip_bf16.h>

typedef float f32x4 __attribute__((ext_vector_type(4)));
typedef _Float16 half8 __attribute__((ext_vector_type(8)));
typedef _Float16 half4 __attribute__((ext_vector_type(4)));
typedef __fp16 cvt2_t __attribute__((ext_vector_type(2)));

#define N_NODES 1024
#define FDIM 64
#define NG 32   // B * Tp = 2 * 16
#define LOG2E 1.44269504088896f

// ---------------- K0: fused prep — 0x00/0xFF byte mask + weight transpose ----------------
__global__ __launch_bounds__(256) void k_prep(const int* __restrict__ adj,
                                              const float* __restrict__ Wh,
                                              const float* __restrict__ Wo,
                                              unsigned char* __restrict__ Mbyte,
                                              _Float16* __restrict__ wt1,
                                              _Float16* __restrict__ wt2) {
    const int bb = blockIdx.x, t = threadIdx.x;
    if (bb < 128) {
        int w = bb * 256 + t;                  // 32768 threads x 32 elements
        const int* p = adj + (size_t)w * 32;
        unsigned r[8];
#pragma unroll
        for (int q = 0; q < 8; q++) {
            int4 a = ((const int4*)p)[q];
            r[q] = (a.x > 0 ? 0xFFu : 0u) | (a.y > 0 ? 0xFFu << 8 : 0u) |
                   (a.z > 0 ? 0xFFu << 16 : 0u) | (a.w > 0 ? 0xFFu << 24 : 0u);
        }
        uint4* dst = (uint4*)(Mbyte + (size_t)w * 32);
        dst[0] = (uint4){r[0], r[1], r[2], r[3]};
        dst[1] = (uint4){r[4], r[5], r[6], r[7]};
    } else if (bb < 132) {
        const int row = (bb - 128) * 64 + (t >> 2);   // 0..255 = h*64+o
        const int kq = t & 3;
        const float* src = Wh + (size_t)(row >> 6) * 4096 + (row & 63);
#pragma unroll
        for (int kk = 0; kk < 16; kk += 8) {
            const int k0 = kq * 16 + kk;
            union { half8 v; cvt2_t c[4]; } pk_;
#pragma unroll
            for (int j = 0; j < 8; j += 2)
                pk_.c[j >> 1] = __builtin_amdgcn_cvt_pkrtz(src[(k0 + j) * 64],
                                                           src[(k0 + j + 1) * 64]);
            *(half8*)(wt1 + (size_t)row * 64 + k0) = pk_.v;
        }
    } else {
        const int o = (bb - 132) * 16 + (t >> 4);     // 0..63
        const int k0 = (t & 15) * 16;
        const float* src = Wo + o;
#pragma unroll
        for (int kk = 0; kk < 16; kk += 8) {
            union { half8 v; cvt2_t c[4]; } pk_;
#pragma unroll
            for (int j = 0; j < 8; j += 2)
                pk_.c[j >> 1] = __builtin_amdgcn_cvt_pkrtz(src[(k0 + kk + j) * 64],
                                                           src[(k0 + kk + j + 1) * 64]);
            *(half8*)(wt2 + (size_t)o * 256 + k0 + kk) = pk_.v;
        }
    }
}

// ---------------- K1: layer-1 projection via fp16 MFMA (4 heads fused) ----------------
// epilogue stores: K=2^(-0.8*phi1), EB=2^phi2, ED=2^(0.2*phi2)  (all f32)
__global__ __launch_bounds__(512, 2) void k_proj1(const float* __restrict__ x,
                                                  const _Float16* __restrict__ wt1,
                                                  const float* __restrict__ ah,
                                                  _Float16* __restrict__ H1T,
                                                  float* __restrict__ Kv,
                                                  float* __restrict__ EB,
                                                  float* __restrict__ ED) {
    __shared__ _Float16 xs[128][64];   // XOR-swizzled 16B units
    const int t = threadIdx.x;
    const int nb = blockIdx.x, g = blockIdx.y;
    const int n0 = nb * 128;
    const int b = g >> 4, tstep = g & 15;

    {   // stage x tile
        const int r = t >> 2, cq = t & 3;
        const float* xr = x + (((size_t)(b * 17 + tstep) * N_NODES + n0 + r) * FDIM) + cq * 16;
        float4 v0 = *(const float4*)(xr);
        float4 v1 = *(const float4*)(xr + 4);
        float4 v2 = *(const float4*)(xr + 8);
        float4 v3 = *(const float4*)(xr + 12);
        union { half8 v; cvt2_t c[4]; } u0, u1;
        u0.c[0] = __builtin_amdgcn_cvt_pkrtz(v0.x, v0.y);
        u0.c[1] = __builtin_amdgcn_cvt_pkrtz(v0.z, v0.w);
        u0.c[2] = __builtin_amdgcn_cvt_pkrtz(v1.x, v1.y);
        u0.c[3] = __builtin_amdgcn_cvt_pkrtz(v1.z, v1.w);
        u1.c[0] = __builtin_amdgcn_cvt_pkrtz(v2.x, v2.y);
        u1.c[1] = __builtin_amdgcn_cvt_pkrtz(v2.z, v2.w);
        u1.c[2] = __builtin_amdgcn_cvt_pkrtz(v3.x, v3.y);
        u1.c[3] = __builtin_amdgcn_cvt_pkrtz(v3.z, v3.w);
        *(half8*)&xs[r][((2 * cq) ^ (r & 7)) * 8] = u0.v;
        *(half8*)&xs[r][((2 * cq + 1) ^ (r & 7)) * 8] = u1.v;
    }
    __syncthreads();

    const int wv = t >> 6, ln = t & 63, li = ln & 15, grp = ln >> 4;
    const int arow = wv * 16 + li;

    f32x4 acc[16];
#pragma unroll
    for (int q = 0; q < 16; q++) acc[q] = (f32x4){0.f, 0.f, 0.f, 0.f};

#pragma unroll
    for (int s = 0; s < 2; s++) {
        half8 af = *(const half8*)&xs[arow][((s * 4 + grp) ^ (arow & 7)) * 8];
#pragma unroll
        for (int tile = 0; tile < 16; tile++) {
            half8 bf = *(const half8*)(wt1 + (size_t)(tile * 16 + li) * 64 + s * 32 + grp * 8);
            acc[tile] = __builtin_amdgcn_mfma_f32_16x16x32_f16(af, bf, acc[tile], 0, 0, 0);
        }
    }

    const int nbase = n0 + wv * 16 + grp * 4;
#pragma unroll
    for (int h = 0; h < 4; h++) {
        float p1[4] = {0.f, 0.f, 0.f, 0.f}, p2[4] = {0.f, 0.f, 0.f, 0.f};
#pragma unroll
        for (int ot = 0; ot < 4; ot++) {
            float a1v = ah[h * 128 + ot * 16 + li];
            float a2v = ah[h * 128 + 64 + ot * 16 + li];
            f32x4 A = acc[h * 4 + ot];
#pragma unroll
            for (int r = 0; r < 4; r++) {
                p1[r] = fmaf(A[r], a1v, p1[r]);
                p2[r] = fmaf(A[r], a2v, p2[r]);
            }
        }
#pragma unroll
        for (int m = 1; m < 16; m <<= 1)
#pragma unroll
            for (int r = 0; r < 4; r++) {
                p1[r] += __shfl_xor(p1[r], m);
                p2[r] += __shfl_xor(p2[r], m);
            }
        if (li == 0) {
            const size_t gh = (size_t)h * NG + g;
#pragma unroll
            for (int r = 0; r < 4; r++) {
                float phi1 = p1[r] * LOG2E, phi2 = p2[r] * LOG2E;
                Kv[gh * N_NODES + nbase + r] = __builtin_amdgcn_exp2f(-0.8f * phi1);
                EB[gh * N_NODES + nbase + r] = __builtin_amdgcn_exp2f(phi2);
                ED[gh * N_NODES + nbase + r] = __builtin_amdgcn_exp2f(0.2f * phi2);
            }
        }
    }
#pragma unroll
    for (int tile = 0; tile < 16; tile++) {
        const int h = tile >> 2, ot = tile & 3;
        union { half4 v; cvt2_t c[2]; } st;
        st.c[0] = __builtin_amdgcn_cvt_pkrtz(acc[tile][0], acc[tile][1]);
        st.c[1] = __builtin_amdgcn_cvt_pkrtz(acc[tile][2], acc[tile][3]);
        _Float16* dst = H1T + (((size_t)h * NG + g) * FDIM + ot * 16 + li) * N_NODES + nbase;
        *(half4*)dst = st.v;
    }
}

// q-pair: fp32 max(EB, K*ED) -> packed fp16 -> AND with perm-expanded byte mask
#define QPAIR(dst, kv, eax, eay, ecx, ecy, wsrc, sel)                          \
    { union { cvt2_t c; unsigned u; } _t;                                      \
      _t.c = __builtin_amdgcn_cvt_pkrtz(fmaxf(eax, (kv) * (ecx)),              \
                                        fmaxf(eay, (kv) * (ecy)));             \
      dst = _t.u & __builtin_amdgcn_perm(wsrc, wsrc, sel); }

// ---------------- fused masked attention (static-offset addressing) ----------------
// NT row-tiles/wave, NW waves; single-buffer XOR-swizzled vt; fp32 scores;
// ALL inner-loop accesses = hoisted base + compile-time immediate offset.
template<int CONCAT, int NT, int NW>
__global__ __launch_bounds__(NW * 64, 4) void k_attn(
    const _Float16* __restrict__ HT,         // [G][64 f][1024 n] f16
    const float* __restrict__ Kv,            // [G][1024] 2^(-0.8 phi1)
    const float* __restrict__ EBg,           // [G][1024] 2^(phi2)
    const float* __restrict__ EDg,           // [G][1024] 2^(0.2 phi2)
    const unsigned char* __restrict__ Mb,    // [1024][1024] byte mask {0,0xFF}
    _Float16* __restrict__ HC,               // concat out (CONCAT=1)
    float* __restrict__ out)                 // final out (CONCAT=0)
{
    __shared__ _Float16 vt[64][256];         // 32KB; unit-XOR swizzle
    __shared__ float ebs[N_NODES];           // 4KB
    __shared__ float eds[N_NODES];           // 4KB
    const int t = threadIdx.x;
    const int g = blockIdx.x, h = blockIdx.y, nb = blockIdx.z;
    const int i0 = nb * (NW * NT * 16);
    const size_t gidx = CONCAT ? ((size_t)h * NG + g) : (size_t)g;

    {   // stage fp32 score vectors
        const float* ebsrc = EBg + gidx * N_NODES;
        const float* edsrc = EDg + gidx * N_NODES;
        if (NW == 8) {
            ((float2*)ebs)[t] = ((const float2*)ebsrc)[t];
            ((float2*)eds)[t] = ((const float2*)edsrc)[t];
        } else {
            ((float4*)ebs)[t] = ((const float4*)ebsrc)[t];
            ((float4*)eds)[t] = ((const float4*)edsrc)[t];
        }
    }

    const int wv = t >> 6, ln = t & 63;
    const int li = ln & 15, grp = ln >> 4, jb = grp * 8;
    const int lx = li & 7;
    const int row0 = i0 + wv * (NT * 16) + li;

    float kv[NT];
    const unsigned char* Mra[NT];
    uint2 m0[NT], m1[NT];
#pragma unroll
    for (int ti = 0; ti < NT; ti++) {
        kv[ti] = Kv[gidx * N_NODES + row0 + ti * 16];
        Mra[ti] = Mb + (size_t)(row0 + ti * 16) * N_NODES + jb;   // FIXED base
    }

    const _Float16* Hg = HT + gidx * (size_t)(FDIM * N_NODES);
    const int srow0 = t >> 3;                     // NW=8: 0..63 ; NW=4: 0..31 (+32)
    const int sxu = t & 7;
    const _Float16* srcA = Hg + (size_t)srow0 * N_NODES + sxu * 8;
    const int swA = sxu ^ (srow0 & 7);
    _Float16* wb0 = &vt[srow0][swA * 8];          // hoisted write base
    _Float16* wb1 = (NW == 4) ? &vt[srow0 + 32][swA * 8] : nullptr;

    // hoisted read bases: B-frag even/odd jc, score vectors
    const int u0g = grp ^ lx;
    const char* vbE = (const char*)&vt[li][u0g * 8];
    const char* vbO = (const char*)&vt[li][(u0g ^ 4) * 8];
    const float* ebb = &ebs[jb];
    const float* edb = &eds[jb];

    f32x4 acc[NT][4], acc5[NT];
#pragma unroll
    for (int ti = 0; ti < NT; ti++) {
#pragma unroll
        for (int q = 0; q < 4; q++) acc[ti][q] = (f32x4){0.f, 0.f, 0.f, 0.f};
        acc5[ti] = (f32x4){0.f, 0.f, 0.f, 0.f};
    }

    union { half8 v; unsigned short s[8]; } onesu;
#pragma unroll
    for (int q = 0; q < 8; q++) onesu.s[q] = 0x3C00;   // fp16 1.0
    const half8 ones = onesu.v;

    half8 stg[NW == 4 ? 8 : 4];
#pragma unroll
    for (int k2 = 0; k2 < 4; k2++) stg[k2] = *(const half8*)(srcA + k2 * 64);
    if (NW == 4) {
#pragma unroll
        for (int k2 = 0; k2 < 4; k2++)
            stg[4 + k2] = *(const half8*)(srcA + 32 * N_NODES + k2 * 64);
    }
#pragma unroll
    for (int ti = 0; ti < NT; ti++) {
        m0[ti] = *(const uint2*)(Mra[ti]);
        m1[ti] = *(const uint2*)(Mra[ti] + 32);
    }

#pragma unroll
    for (int jt = 0; jt < 4; jt++) {
        __syncthreads();                      // all waves done reading vt
#pragma unroll
        for (int k2 = 0; k2 < 4; k2++)
            *(half8*)((char*)wb0 + k2 * 128) = stg[k2];
        if (NW == 4) {
#pragma unroll
            for (int k2 = 0; k2 < 4; k2++)
                *(half8*)((char*)wb1 + k2 * 128) = stg[4 + k2];
        }
        if (jt < 3) {                         // issue next tile's loads (static offsets)
#pragma unroll
            for (int k2 = 0; k2 < 4; k2++)
                stg[k2] = *(const half8*)(srcA + (jt + 1) * 256 + k2 * 64);
            if (NW == 4) {
#pragma unroll
                for (int k2 = 0; k2 < 4; k2++)
                    stg[4 + k2] = *(const half8*)(srcA + 32 * N_NODES + (jt + 1) * 256 + k2 * 64);
            }
        }
        __syncthreads();                      // vt fully written

#pragma unroll
        for (int jc = 0; jc < 8; jc++) {
            uint2 w[NT];
#pragma unroll
            for (int ti = 0; ti < NT; ti++) {
                w[ti] = m0[ti];
                m0[ti] = m1[ti];
                if (!(jt == 3 && jc >= 6))    // static guard; static offset load
                    m1[ti] = *(const uint2*)(Mra[ti] + jt * 256 + jc * 32 + 64);
            }

            const int so = jt * 256 + jc * 32;            // static float offset
            float4 ea0 = *(const float4*)(ebb + so);
            float4 ea1 = *(const float4*)(ebb + so + 4);
            float4 ec0 = *(const float4*)(edb + so);
            float4 ec1 = *(const float4*)(edb + so + 4);

            union { half8 v; unsigned u[4]; } af[NT];
#pragma unroll
            for (int ti = 0; ti < NT; ti++) {
                QPAIR(af[ti].u[0], kv[ti], ea0.x, ea0.y, ec0.x, ec0.y, w[ti].x, 0x01010000u);
                QPAIR(af[ti].u[1], kv[ti], ea0.z, ea0.w, ec0.z, ec0.w, w[ti].x, 0x03030202u);
                QPAIR(af[ti].u[2], kv[ti], ea1.x, ea1.y, ec1.x, ec1.y, w[ti].y, 0x01010000u);
                QPAIR(af[ti].u[3], kv[ti], ea1.z, ea1.w, ec1.z, ec1.w, w[ti].y, 0x03030202u);
            }

            // B-frag: hoisted base (even/odd jc) + static byte offset
            const char* vb = (jc & 1) ? vbO : vbE;
            const int boff = (jc >> 1) * 128;
#pragma unroll
            for (int q = 0; q < 4; q++) {     // B-frag shared by all row-tiles
                half8 bfr = *(const half8*)(vb + boff + q * 8192);
#pragma unroll
                for (int ti = 0; ti < NT; ti++)
                    acc[ti][q] = __builtin_amdgcn_mfma_f32_16x16x32_f16(af[ti].v, bfr, acc[ti][q], 0, 0, 0);
            }
#pragma unroll
            for (int ti = 0; ti < NT; ti++)
                acc5[ti] = __builtin_amdgcn_mfma_f32_16x16x32_f16(af[ti].v, ones, acc5[ti], 0, 0, 0);
        }
    }

#pragma unroll
    for (int ti = 0; ti < NT; ti++) {
        float rin[4];
#pragma unroll
        for (int r2 = 0; r2 < 4; r2++) rin[r2] = 1.0f / acc5[ti][r2];
        if (CONCAT) {
            _Float16* HCg = HC + (size_t)g * N_NODES * 256 + h * 64;
#pragma unroll
            for (int q = 0; q < 4; q++)
#pragma unroll
                for (int r2 = 0; r2 < 4; r2++) {
                    int ir = i0 + wv * (NT * 16) + ti * 16 + grp * 4 + r2;
                    float v = acc[ti][q][r2] * rin[r2];
                    v = v > 0.f ? v : expm1f(v); // ELU
                    HCg[(size_t)ir * 256 + q * 16 + li] = (_Float16)v;
                }
        } else {
            float* og = out + (size_t)g * N_NODES * FDIM;
#pragma unroll
            for (int q = 0; q < 4; q++)
#pragma unroll
                for (int r2 = 0; r2 < 4; r2++) {
                    int ir = i0 + wv * (NT * 16) + ti * 16 + grp * 4 + r2;
                    float v = acc[ti][q][r2] * rin[r2];
                    og[(size_t)ir * FDIM + q * 16 + li] = v > 0.f ? v : 0.f;
                }
        }
    }
}

// ---------------- K3: layer-2 projection via fp16 MFMA ----------------
__global__ __launch_bounds__(512, 2) void k_proj2(const _Float16* __restrict__ HC,
                                                  const _Float16* __restrict__ wt2,
                                                  const float* __restrict__ ao,
                                                  _Float16* __restrict__ H2T,
                                                  float* __restrict__ Kv2,
                                                  float* __restrict__ EB2,
                                                  float* __restrict__ ED2) {
    __shared__ _Float16 xs[128][256];  // 64KB, XOR-swizzled within 8-unit groups
    const int t = threadIdx.x;
    const int nb = blockIdx.x, g = blockIdx.y;
    const int n0 = nb * 128;

    {   // stage HC tile
        const int r = t >> 2, cq = t & 3;
        const _Float16* src = HC + ((size_t)g * N_NODES + n0 + r) * 256 + cq * 64;
#pragma unroll
        for (int uu = 0; uu < 8; uu++) {
            int u = cq * 8 + uu;
            half8 v = *(const half8*)(src + uu * 8);
            int us = (u & 24) | ((u ^ r) & 7);
            *(half8*)&xs[r][us * 8] = v;
        }
    }
    __syncthreads();

    const int wv = t >> 6, ln = t & 63, li = ln & 15, grp = ln >> 4;
    const int arow = wv * 16 + li;

    f32x4 acc[4];
#pragma unroll
    for (int q = 0; q < 4; q++) acc[q] = (f32x4){0.f, 0.f, 0.f, 0.f};

#pragma unroll
    for (int s = 0; s < 8; s++) {
        int u = s * 4 + grp;
        int us = (u & 24) | ((u ^ arow) & 7);
        half8 af = *(const half8*)&xs[arow][us * 8];
#pragma unroll
        for (int tile = 0; tile < 4; tile++) {
            half8 bf = *(const half8*)(wt2 + (size_t)(tile * 16 + li) * 256 + s * 32 + grp * 8);
            acc[tile] = __builtin_amdgcn_mfma_f32_16x16x32_f16(af, bf, acc[tile], 0, 0, 0);
        }
    }

    const int nbase = n0 + wv * 16 + grp * 4;
    {
        float p1[4] = {0.f, 0.f, 0.f, 0.f}, p2[4] = {0.f, 0.f, 0.f, 0.f};
#pragma unroll
        for (int ot = 0; ot < 4; ot++) {
            float a1v = ao[ot * 16 + li];
            float a2v = ao[64 + ot * 16 + li];
            f32x4 A = acc[ot];
#pragma unroll
            for (int r = 0; r < 4; r++) {
                p1[r] = fmaf(A[r], a1v, p1[r]);
                p2[r] = fmaf(A[r], a2v, p2[r]);
            }
        }
#pragma unroll
        for (int m = 1; m < 16; m <<= 1)
#pragma unroll
            for (int r = 0; r < 4; r++) {
                p1[r] += __shfl_xor(p1[r], m);
                p2[r] += __shfl_xor(p2[r], m);
            }
        if (li == 0) {
#pragma unroll
            for (int r = 0; r < 4; r++) {
                float phi1 = p1[r] * LOG2E, phi2 = p2[r] * LOG2E;
                Kv2[(size_t)g * N_NODES + nbase + r] = __builtin_amdgcn_exp2f(-0.8f * phi1);
                EB2[(size_t)g * N_NODES + nbase + r] = __builtin_amdgcn_exp2f(phi2);
                ED2[(size_t)g * N_NODES + nbase + r] = __builtin_amdgcn_exp2f(0.2f * phi2);
            }
        }
    }
#pragma unroll
    for (int tile = 0; tile < 4; tile++) {
        union { half4 v; cvt2_t c[2]; } st;
        st.c[0] = __builtin_amdgcn_cvt_pkrtz(acc[tile][0], acc[tile][1]);
        st.c[1] = __builtin_amdgcn_cvt_pkrtz(acc[tile][2], acc[tile][3]);
        _Float16* dst = H2T + ((size_t)g * FDIM + tile * 16 + li) * N_NODES + nbase;
        *(half4*)dst = st.v;
    }
}

extern "C" void kernel_launch(void* const* d_in, const int* in_sizes, int n_in,
                              void* d_out, int out_size, void* d_ws, size_t ws_size,
                              hipStream_t stream) {
    const float* x  = (const float*)d_in[0];
    const int* adj  = (const int*)d_in[1];
    const float* Wh = (const float*)d_in[2];
    const float* ah = (const float*)d_in[3];
    const float* Wo = (const float*)d_in[4];
    const float* ao = (const float*)d_in[5];

    char* ws = (char*)d_ws;
    unsigned char* Mbyte = (unsigned char*)(ws);             // 1 MB
    _Float16* wt1 = (_Float16*)(ws + 1048576);               // 32 KB
    _Float16* wt2 = (_Float16*)(ws + 1081344);               // 32 KB
    float* Kv1 = (float*)(ws + 1114112);                     // 512 KB
    float* EB1 = (float*)(ws + 1638400);                     // 512 KB
    float* ED1 = (float*)(ws + 2162688);                     // 512 KB
    float* Kv2 = (float*)(ws + 2686976);                     // 128 KB
    float* EB2 = (float*)(ws + 2818048);                     // 128 KB
    float* ED2 = (float*)(ws + 2949120);                     // 128 KB
    _Float16* H1T = (_Float16*)(ws + 3080192);               // 16 MB
    _Float16* HC  = (_Float16*)(ws + 3080192 + 16777216);    // 16 MB
    _Float16* H2T = (_Float16*)(ws + 3080192 + 33554432);    //  4 MB
    float* out = (float*)d_out;

    k_prep       <<<dim3(136),       dim3(256), 0, stream>>>(adj, Wh, Wo, Mbyte, wt1, wt2);
    k_proj1      <<<dim3(8, 32),     dim3(512), 0, stream>>>(x, wt1, ah, H1T, Kv1, EB1, ED1);
    k_attn<1,2,8><<<dim3(32, 4, 4),  dim3(512), 0, stream>>>(H1T, Kv1, EB1, ED1, Mbyte, HC, nullptr);
    k_proj2      <<<dim3(8, 32),     dim3(512), 0, stream>>>(HC, wt2, ao, H2T, Kv2, EB2, ED2);
    k_attn<0,1,4><<<dim3(32, 1, 16), dim3(256), 0, stream>>>(H2T, Kv2, EB2, ED2, Mbyte, nullptr, out);
}

// Round 18
// 92.653 us; speedup vs baseline: 1.0919x; 1.0534x over previous
//
#include <hip/hip_runtime.h>
#include <hip/hip_bf16.h>

typedef float f32x4 __attribute__((ext_vector_type(4)));
typedef _Float16 half8 __attribute__((ext_vector_type(8)));
typedef _Float16 half4 __attribute__((ext_vector_type(4)));
typedef __fp16 cvt2_t __attribute__((ext_vector_type(2)));

#define N_NODES 1024
#define FDIM 64
#define NG 32   // B * Tp = 2 * 16
#define LOG2E 1.44269504088896f

// ---------------- K0: fused prep — 0x00/0xFF byte mask + weight transpose ----------------
__global__ __launch_bounds__(256) void k_prep(const int* __restrict__ adj,
                                              const float* __restrict__ Wh,
                                              const float* __restrict__ Wo,
                                              unsigned char* __restrict__ Mbyte,
                                              _Float16* __restrict__ wt1,
                                              _Float16* __restrict__ wt2) {
    const int bb = blockIdx.x, t = threadIdx.x;
    if (bb < 128) {
        int w = bb * 256 + t;                  // 32768 threads x 32 elements
        const int* p = adj + (size_t)w * 32;
        unsigned r[8];
#pragma unroll
        for (int q = 0; q < 8; q++) {
            int4 a = ((const int4*)p)[q];
            r[q] = (a.x > 0 ? 0xFFu : 0u) | (a.y > 0 ? 0xFFu << 8 : 0u) |
                   (a.z > 0 ? 0xFFu << 16 : 0u) | (a.w > 0 ? 0xFFu << 24 : 0u);
        }
        uint4* dst = (uint4*)(Mbyte + (size_t)w * 32);
        dst[0] = (uint4){r[0], r[1], r[2], r[3]};
        dst[1] = (uint4){r[4], r[5], r[6], r[7]};
    } else if (bb < 132) {
        const int row = (bb - 128) * 64 + (t >> 2);   // 0..255 = h*64+o
        const int kq = t & 3;
        const float* src = Wh + (size_t)(row >> 6) * 4096 + (row & 63);
#pragma unroll
        for (int kk = 0; kk < 16; kk += 8) {
            const int k0 = kq * 16 + kk;
            union { half8 v; cvt2_t c[4]; } pk_;
#pragma unroll
            for (int j = 0; j < 8; j += 2)
                pk_.c[j >> 1] = __builtin_amdgcn_cvt_pkrtz(src[(k0 + j) * 64],
                                                           src[(k0 + j + 1) * 64]);
            *(half8*)(wt1 + (size_t)row * 64 + k0) = pk_.v;
        }
    } else {
        const int o = (bb - 132) * 16 + (t >> 4);     // 0..63
        const int k0 = (t & 15) * 16;
        const float* src = Wo + o;
#pragma unroll
        for (int kk = 0; kk < 16; kk += 8) {
            union { half8 v; cvt2_t c[4]; } pk_;
#pragma unroll
            for (int j = 0; j < 8; j += 2)
                pk_.c[j >> 1] = __builtin_amdgcn_cvt_pkrtz(src[(k0 + kk + j) * 64],
                                                           src[(k0 + kk + j + 1) * 64]);
            *(half8*)(wt2 + (size_t)o * 256 + k0 + kk) = pk_.v;
        }
    }
}

// ---------------- K1: layer-1 projection via fp16 MFMA (4 heads fused) ----------------
// epilogue stores: K=2^(-0.8*phi1), EB=2^phi2, ED=2^(0.2*phi2)  (all f32)
__global__ __launch_bounds__(512, 2) void k_proj1(const float* __restrict__ x,
                                                  const _Float16* __restrict__ wt1,
                                                  const float* __restrict__ ah,
                                                  _Float16* __restrict__ H1T,
                                                  float* __restrict__ Kv,
                                                  float* __restrict__ EB,
                                                  float* __restrict__ ED) {
    __shared__ _Float16 xs[128][64];   // XOR-swizzled 16B units
    const int t = threadIdx.x;
    const int nb = blockIdx.x, g = blockIdx.y;
    const int n0 = nb * 128;
    const int b = g >> 4, tstep = g & 15;

    {   // stage x tile
        const int r = t >> 2, cq = t & 3;
        const float* xr = x + (((size_t)(b * 17 + tstep) * N_NODES + n0 + r) * FDIM) + cq * 16;
        float4 v0 = *(const float4*)(xr);
        float4 v1 = *(const float4*)(xr + 4);
        float4 v2 = *(const float4*)(xr + 8);
        float4 v3 = *(const float4*)(xr + 12);
        union { half8 v; cvt2_t c[4]; } u0, u1;
        u0.c[0] = __builtin_amdgcn_cvt_pkrtz(v0.x, v0.y);
        u0.c[1] = __builtin_amdgcn_cvt_pkrtz(v0.z, v0.w);
        u0.c[2] = __builtin_amdgcn_cvt_pkrtz(v1.x, v1.y);
        u0.c[3] = __builtin_amdgcn_cvt_pkrtz(v1.z, v1.w);
        u1.c[0] = __builtin_amdgcn_cvt_pkrtz(v2.x, v2.y);
        u1.c[1] = __builtin_amdgcn_cvt_pkrtz(v2.z, v2.w);
        u1.c[2] = __builtin_amdgcn_cvt_pkrtz(v3.x, v3.y);
        u1.c[3] = __builtin_amdgcn_cvt_pkrtz(v3.z, v3.w);
        *(half8*)&xs[r][((2 * cq) ^ (r & 7)) * 8] = u0.v;
        *(half8*)&xs[r][((2 * cq + 1) ^ (r & 7)) * 8] = u1.v;
    }
    __syncthreads();

    const int wv = t >> 6, ln = t & 63, li = ln & 15, grp = ln >> 4;
    const int arow = wv * 16 + li;

    f32x4 acc[16];
#pragma unroll
    for (int q = 0; q < 16; q++) acc[q] = (f32x4){0.f, 0.f, 0.f, 0.f};

#pragma unroll
    for (int s = 0; s < 2; s++) {
        half8 af = *(const half8*)&xs[arow][((s * 4 + grp) ^ (arow & 7)) * 8];
#pragma unroll
        for (int tile = 0; tile < 16; tile++) {
            half8 bf = *(const half8*)(wt1 + (size_t)(tile * 16 + li) * 64 + s * 32 + grp * 8);
            acc[tile] = __builtin_amdgcn_mfma_f32_16x16x32_f16(af, bf, acc[tile], 0, 0, 0);
        }
    }

    const int nbase = n0 + wv * 16 + grp * 4;
#pragma unroll
    for (int h = 0; h < 4; h++) {
        float p1[4] = {0.f, 0.f, 0.f, 0.f}, p2[4] = {0.f, 0.f, 0.f, 0.f};
#pragma unroll
        for (int ot = 0; ot < 4; ot++) {
            float a1v = ah[h * 128 + ot * 16 + li];
            float a2v = ah[h * 128 + 64 + ot * 16 + li];
            f32x4 A = acc[h * 4 + ot];
#pragma unroll
            for (int r = 0; r < 4; r++) {
                p1[r] = fmaf(A[r], a1v, p1[r]);
                p2[r] = fmaf(A[r], a2v, p2[r]);
            }
        }
#pragma unroll
        for (int m = 1; m < 16; m <<= 1)
#pragma unroll
            for (int r = 0; r < 4; r++) {
                p1[r] += __shfl_xor(p1[r], m);
                p2[r] += __shfl_xor(p2[r], m);
            }
        if (li == 0) {
            const size_t gh = (size_t)h * NG + g;
#pragma unroll
            for (int r = 0; r < 4; r++) {
                float phi1 = p1[r] * LOG2E, phi2 = p2[r] * LOG2E;
                Kv[gh * N_NODES + nbase + r] = __builtin_amdgcn_exp2f(-0.8f * phi1);
                EB[gh * N_NODES + nbase + r] = __builtin_amdgcn_exp2f(phi2);
                ED[gh * N_NODES + nbase + r] = __builtin_amdgcn_exp2f(0.2f * phi2);
            }
        }
    }
#pragma unroll
    for (int tile = 0; tile < 16; tile++) {
        const int h = tile >> 2, ot = tile & 3;
        union { half4 v; cvt2_t c[2]; } st;
        st.c[0] = __builtin_amdgcn_cvt_pkrtz(acc[tile][0], acc[tile][1]);
        st.c[1] = __builtin_amdgcn_cvt_pkrtz(acc[tile][2], acc[tile][3]);
        _Float16* dst = H1T + (((size_t)h * NG + g) * FDIM + ot * 16 + li) * N_NODES + nbase;
        *(half4*)dst = st.v;
    }
}

// q-pair: fp32 max(EB, K*ED) -> packed fp16 -> AND with perm-expanded byte mask
#define QPAIR(dst, kv, eax, eay, ecx, ecy, wsrc, sel)                          \
    { union { cvt2_t c; unsigned u; } _t;                                      \
      _t.c = __builtin_amdgcn_cvt_pkrtz(fmaxf(eax, (kv) * (ecx)),              \
                                        fmaxf(eay, (kv) * (ecy)));             \
      dst = _t.u & __builtin_amdgcn_perm(wsrc, wsrc, sel); }

// ---------------- fused masked attention (NW waves, NT row-tiles/wave) ----------------
// Single-buffer XOR-swizzled vt; fp32 scores; perm-AND byte mask;
// ones-MFMA row-sums; T5 setprio around MFMA clusters.
template<int CONCAT, int NT, int NW>
__global__ __launch_bounds__(NW * 64, 2) void k_attn(
    const _Float16* __restrict__ HT,         // [G][64 f][1024 n] f16
    const float* __restrict__ Kv,            // [G][1024] 2^(-0.8 phi1)
    const float* __restrict__ EBg,           // [G][1024] 2^(phi2)
    const float* __restrict__ EDg,           // [G][1024] 2^(0.2 phi2)
    const unsigned char* __restrict__ Mb,    // [1024][1024] byte mask {0,0xFF}
    _Float16* __restrict__ HC,               // concat out (CONCAT=1)
    float* __restrict__ out)                 // final out (CONCAT=0)
{
    __shared__ _Float16 vt[64][256];         // 32KB; unit-XOR swizzle
    __shared__ float ebs[N_NODES];           // 4KB
    __shared__ float eds[N_NODES];           // 4KB
    const int t = threadIdx.x;
    const int g = blockIdx.x, h = blockIdx.y, nb = blockIdx.z;
    const int i0 = nb * (NW * NT * 16);
    const size_t gidx = CONCAT ? ((size_t)h * NG + g) : (size_t)g;

    {   // stage fp32 score vectors
        const float* ebsrc = EBg + gidx * N_NODES;
        const float* edsrc = EDg + gidx * N_NODES;
        if (NW == 8) {
            ((float2*)ebs)[t] = ((const float2*)ebsrc)[t];
            ((float2*)eds)[t] = ((const float2*)edsrc)[t];
        } else {
            ((float4*)ebs)[t] = ((const float4*)ebsrc)[t];
            ((float4*)eds)[t] = ((const float4*)edsrc)[t];
        }
    }

    const int wv = t >> 6, ln = t & 63;
    const int li = ln & 15, grp = ln >> 4, jb = grp * 8;
    const int lx = li & 7;
    const int row0 = i0 + wv * (NT * 16) + li;

    float kv[NT];
    const unsigned char* Mra[NT];
    uint2 m0[NT], m1[NT];
#pragma unroll
    for (int ti = 0; ti < NT; ti++) {
        kv[ti] = Kv[gidx * N_NODES + row0 + ti * 16];
        Mra[ti] = Mb + (size_t)(row0 + ti * 16) * N_NODES + jb;   // FIXED base
    }

    const _Float16* Hg = HT + gidx * (size_t)(FDIM * N_NODES);
    const int srow0 = t >> 3;                     // NW=8: 0..63 ; NW=4: 0..31 (+32)
    const int sxu = t & 7;
    const _Float16* srcA = Hg + (size_t)srow0 * N_NODES + sxu * 8;
    const int swA = sxu ^ (srow0 & 7);
    _Float16* wb0 = &vt[srow0][swA * 8];          // hoisted write base
    _Float16* wb1 = (NW == 4) ? &vt[srow0 + 32][swA * 8] : nullptr;

    // hoisted read bases: B-frag even/odd jc, score vectors
    const int u0g = grp ^ lx;
    const char* vbE = (const char*)&vt[li][u0g * 8];
    const char* vbO = (const char*)&vt[li][(u0g ^ 4) * 8];
    const float* ebb = &ebs[jb];
    const float* edb = &eds[jb];

    f32x4 acc[NT][4], acc5[NT];
#pragma unroll
    for (int ti = 0; ti < NT; ti++) {
#pragma unroll
        for (int q = 0; q < 4; q++) acc[ti][q] = (f32x4){0.f, 0.f, 0.f, 0.f};
        acc5[ti] = (f32x4){0.f, 0.f, 0.f, 0.f};
    }

    union { half8 v; unsigned short s[8]; } onesu;
#pragma unroll
    for (int q = 0; q < 8; q++) onesu.s[q] = 0x3C00;   // fp16 1.0
    const half8 ones = onesu.v;

    half8 stg[NW == 4 ? 8 : 4];
#pragma unroll
    for (int k2 = 0; k2 < 4; k2++) stg[k2] = *(const half8*)(srcA + k2 * 64);
    if (NW == 4) {
#pragma unroll
        for (int k2 = 0; k2 < 4; k2++)
            stg[4 + k2] = *(const half8*)(srcA + 32 * N_NODES + k2 * 64);
    }
#pragma unroll
    for (int ti = 0; ti < NT; ti++) {
        m0[ti] = *(const uint2*)(Mra[ti]);
        m1[ti] = *(const uint2*)(Mra[ti] + 32);
    }

#pragma unroll
    for (int jt = 0; jt < 4; jt++) {
        __syncthreads();                      // all waves done reading vt
#pragma unroll
        for (int k2 = 0; k2 < 4; k2++)
            *(half8*)((char*)wb0 + k2 * 128) = stg[k2];
        if (NW == 4) {
#pragma unroll
            for (int k2 = 0; k2 < 4; k2++)
                *(half8*)((char*)wb1 + k2 * 128) = stg[4 + k2];
        }
        if (jt < 3) {                         // issue next tile's loads (static offsets)
#pragma unroll
            for (int k2 = 0; k2 < 4; k2++)
                stg[k2] = *(const half8*)(srcA + (jt + 1) * 256 + k2 * 64);
            if (NW == 4) {
#pragma unroll
                for (int k2 = 0; k2 < 4; k2++)
                    stg[4 + k2] = *(const half8*)(srcA + 32 * N_NODES + (jt + 1) * 256 + k2 * 64);
            }
        }
        __syncthreads();                      // vt fully written

#pragma unroll
        for (int jc = 0; jc < 8; jc++) {
            uint2 w[NT];
#pragma unroll
            for (int ti = 0; ti < NT; ti++) {
                w[ti] = m0[ti];
                m0[ti] = m1[ti];
                if (!(jt == 3 && jc >= 6))    // static guard; static offset load
                    m1[ti] = *(const uint2*)(Mra[ti] + jt * 256 + jc * 32 + 64);
            }

            const int so = jt * 256 + jc * 32;            // static float offset
            float4 ea0 = *(const float4*)(ebb + so);
            float4 ea1 = *(const float4*)(ebb + so + 4);
            float4 ec0 = *(const float4*)(edb + so);
            float4 ec1 = *(const float4*)(edb + so + 4);

            union { half8 v; unsigned u[4]; } af[NT];
#pragma unroll
            for (int ti = 0; ti < NT; ti++) {
                QPAIR(af[ti].u[0], kv[ti], ea0.x, ea0.y, ec0.x, ec0.y, w[ti].x, 0x01010000u);
                QPAIR(af[ti].u[1], kv[ti], ea0.z, ea0.w, ec0.z, ec0.w, w[ti].x, 0x03030202u);
                QPAIR(af[ti].u[2], kv[ti], ea1.x, ea1.y, ec1.x, ec1.y, w[ti].y, 0x01010000u);
                QPAIR(af[ti].u[3], kv[ti], ea1.z, ea1.w, ec1.z, ec1.w, w[ti].y, 0x03030202u);
            }

            // B-frag: hoisted base (even/odd jc) + static byte offset
            const char* vb = (jc & 1) ? vbO : vbE;
            const int boff = (jc >> 1) * 128;
            __builtin_amdgcn_s_setprio(1);    // T5: favor MFMA-entering wave
#pragma unroll
            for (int q = 0; q < 4; q++) {     // B-frag shared by all row-tiles
                half8 bfr = *(const half8*)(vb + boff + q * 8192);
#pragma unroll
                for (int ti = 0; ti < NT; ti++)
                    acc[ti][q] = __builtin_amdgcn_mfma_f32_16x16x32_f16(af[ti].v, bfr, acc[ti][q], 0, 0, 0);
            }
#pragma unroll
            for (int ti = 0; ti < NT; ti++)
                acc5[ti] = __builtin_amdgcn_mfma_f32_16x16x32_f16(af[ti].v, ones, acc5[ti], 0, 0, 0);
            __builtin_amdgcn_s_setprio(0);
        }
    }

#pragma unroll
    for (int ti = 0; ti < NT; ti++) {
        float rin[4];
#pragma unroll
        for (int r2 = 0; r2 < 4; r2++) rin[r2] = 1.0f / acc5[ti][r2];
        if (CONCAT) {
            _Float16* HCg = HC + (size_t)g * N_NODES * 256 + h * 64;
#pragma unroll
            for (int q = 0; q < 4; q++)
#pragma unroll
                for (int r2 = 0; r2 < 4; r2++) {
                    int ir = i0 + wv * (NT * 16) + ti * 16 + grp * 4 + r2;
                    float v = acc[ti][q][r2] * rin[r2];
                    v = v > 0.f ? v : expm1f(v); // ELU
                    HCg[(size_t)ir * 256 + q * 16 + li] = (_Float16)v;
                }
        } else {
            float* og = out + (size_t)g * N_NODES * FDIM;
#pragma unroll
            for (int q = 0; q < 4; q++)
#pragma unroll
                for (int r2 = 0; r2 < 4; r2++) {
                    int ir = i0 + wv * (NT * 16) + ti * 16 + grp * 4 + r2;
                    float v = acc[ti][q][r2] * rin[r2];
                    og[(size_t)ir * FDIM + q * 16 + li] = v > 0.f ? v : 0.f;
                }
        }
    }
}

// ---------------- K3: layer-2 projection via fp16 MFMA ----------------
__global__ __launch_bounds__(512, 2) void k_proj2(const _Float16* __restrict__ HC,
                                                  const _Float16* __restrict__ wt2,
                                                  const float* __restrict__ ao,
                                                  _Float16* __restrict__ H2T,
                                                  float* __restrict__ Kv2,
                                                  float* __restrict__ EB2,
                                                  float* __restrict__ ED2) {
    __shared__ _Float16 xs[128][256];  // 64KB, XOR-swizzled within 8-unit groups
    const int t = threadIdx.x;
    const int nb = blockIdx.x, g = blockIdx.y;
    const int n0 = nb * 128;

    {   // stage HC tile
        const int r = t >> 2, cq = t & 3;
        const _Float16* src = HC + ((size_t)g * N_NODES + n0 + r) * 256 + cq * 64;
#pragma unroll
        for (int uu = 0; uu < 8; uu++) {
            int u = cq * 8 + uu;
            half8 v = *(const half8*)(src + uu * 8);
            int us = (u & 24) | ((u ^ r) & 7);
            *(half8*)&xs[r][us * 8] = v;
        }
    }
    __syncthreads();

    const int wv = t >> 6, ln = t & 63, li = ln & 15, grp = ln >> 4;
    const int arow = wv * 16 + li;

    f32x4 acc[4];
#pragma unroll
    for (int q = 0; q < 4; q++) acc[q] = (f32x4){0.f, 0.f, 0.f, 0.f};

#pragma unroll
    for (int s = 0; s < 8; s++) {
        int u = s * 4 + grp;
        int us = (u & 24) | ((u ^ arow) & 7);
        half8 af = *(const half8*)&xs[arow][us * 8];
#pragma unroll
        for (int tile = 0; tile < 4; tile++) {
            half8 bf = *(const half8*)(wt2 + (size_t)(tile * 16 + li) * 256 + s * 32 + grp * 8);
            acc[tile] = __builtin_amdgcn_mfma_f32_16x16x32_f16(af, bf, acc[tile], 0, 0, 0);
        }
    }

    const int nbase = n0 + wv * 16 + grp * 4;
    {
        float p1[4] = {0.f, 0.f, 0.f, 0.f}, p2[4] = {0.f, 0.f, 0.f, 0.f};
#pragma unroll
        for (int ot = 0; ot < 4; ot++) {
            float a1v = ao[ot * 16 + li];
            float a2v = ao[64 + ot * 16 + li];
            f32x4 A = acc[ot];
#pragma unroll
            for (int r = 0; r < 4; r++) {
                p1[r] = fmaf(A[r], a1v, p1[r]);
                p2[r] = fmaf(A[r], a2v, p2[r]);
            }
        }
#pragma unroll
        for (int m = 1; m < 16; m <<= 1)
#pragma unroll
            for (int r = 0; r < 4; r++) {
                p1[r] += __shfl_xor(p1[r], m);
                p2[r] += __shfl_xor(p2[r], m);
            }
        if (li == 0) {
#pragma unroll
            for (int r = 0; r < 4; r++) {
                float phi1 = p1[r] * LOG2E, phi2 = p2[r] * LOG2E;
                Kv2[(size_t)g * N_NODES + nbase + r] = __builtin_amdgcn_exp2f(-0.8f * phi1);
                EB2[(size_t)g * N_NODES + nbase + r] = __builtin_amdgcn_exp2f(phi2);
                ED2[(size_t)g * N_NODES + nbase + r] = __builtin_amdgcn_exp2f(0.2f * phi2);
            }
        }
    }
#pragma unroll
    for (int tile = 0; tile < 4; tile++) {
        union { half4 v; cvt2_t c[2]; } st;
        st.c[0] = __builtin_amdgcn_cvt_pkrtz(acc[tile][0], acc[tile][1]);
        st.c[1] = __builtin_amdgcn_cvt_pkrtz(acc[tile][2], acc[tile][3]);
        _Float16* dst = H2T + ((size_t)g * FDIM + tile * 16 + li) * N_NODES + nbase;
        *(half4*)dst = st.v;
    }
}

extern "C" void kernel_launch(void* const* d_in, const int* in_sizes, int n_in,
                              void* d_out, int out_size, void* d_ws, size_t ws_size,
                              hipStream_t stream) {
    const float* x  = (const float*)d_in[0];
    const int* adj  = (const int*)d_in[1];
    const float* Wh = (const float*)d_in[2];
    const float* ah = (const float*)d_in[3];
    const float* Wo = (const float*)d_in[4];
    const float* ao = (const float*)d_in[5];

    char* ws = (char*)d_ws;
    unsigned char* Mbyte = (unsigned char*)(ws);             // 1 MB
    _Float16* wt1 = (_Float16*)(ws + 1048576);               // 32 KB
    _Float16* wt2 = (_Float16*)(ws + 1081344);               // 32 KB
    float* Kv1 = (float*)(ws + 1114112);                     // 512 KB
    float* EB1 = (float*)(ws + 1638400);                     // 512 KB
    float* ED1 = (float*)(ws + 2162688);                     // 512 KB
    float* Kv2 = (float*)(ws + 2686976);                     // 128 KB
    float* EB2 = (float*)(ws + 2818048);                     // 128 KB
    float* ED2 = (float*)(ws + 2949120);                     // 128 KB
    _Float16* H1T = (_Float16*)(ws + 3080192);               // 16 MB
    _Float16* HC  = (_Float16*)(ws + 3080192 + 16777216);    // 16 MB
    _Float16* H2T = (_Float16*)(ws + 3080192 + 33554432);    //  4 MB
    float* out = (float*)d_out;

    k_prep       <<<dim3(136),       dim3(256), 0, stream>>>(adj, Wh, Wo, Mbyte, wt1, wt2);
    k_proj1      <<<dim3(8, 32),     dim3(512), 0, stream>>>(x, wt1, ah, H1T, Kv1, EB1, ED1);
    k_attn<1,2,8><<<dim3(32, 4, 4),  dim3(512), 0, stream>>>(H1T, Kv1, EB1, ED1, Mbyte, HC, nullptr);
    k_proj2      <<<dim3(8, 32),     dim3(512), 0, stream>>>(HC, wt2, ao, H2T, Kv2, EB2, ED2);
    k_attn<0,1,8><<<dim3(32, 1, 8),  dim3(512), 0, stream>>>(H2T, Kv2, EB2, ED2, Mbyte, nullptr, out);
}